// Round 4
// baseline (356.203 us; speedup 1.0000x reference)
//
#include <hip/hip_runtime.h>
#include <math.h>

// Problem constants (B=16, C=2, H=1024, W=1024)
#define HW   (1024 * 1024)          // H*W = 1M (power of two)
#define NPIX (16 * HW)              // B*H*W = 16,777,216
#define NGRP (NPIX / 4)             // float4 groups over pixel space = 4,194,304

constexpr int THREADS   = 256;
constexpr int NBLK      = 2048;                    // 8 blocks/CU, grid-stride
constexpr int TOTALTHR  = NBLK * THREADS;          // 524,288 threads
constexpr int ITERS     = NGRP / TOTALTHR;         // 8 float4-groups per thread
static_assert(ITERS * TOTALTHR == NGRP, "exact tiling");
// Address streams advance by compile-time constants per iteration because
// 4*TOTALTHR (2^21) is a multiple of HW (2^20):
//   mask/scale ptr += 2*HW elements;  pred/truth ptr += 4*HW elements.
static_assert((4 * TOTALTHR) % HW == 0, "uniform per-iter pointer stride");

__device__ __forceinline__ float fast_sigmoid(float x) {
    return __builtin_amdgcn_rcpf(1.0f + __expf(-x));
}

__device__ __forceinline__ float elem_loss(float x0, float x1, float t0, float t1) {
    float p0 = fast_sigmoid(x0);
    float p1 = fast_sigmoid(x1);
    // p0,p1 in (0,1): e^p in (1,e), no stabilization needed
    float lse = __logf(__expf(p0) + __expf(p1));
    return (t0 + t1) * lse - (t0 * p0 + t1 * p1);
}

// Latency-bound fix (R3 counters: VGPR=32, VALUBusy 13.5%, HBM 19%):
// explicit prefetch-distance-1 software pipeline. Next iteration's 6 float4
// loads are ISSUED before the current iteration's values are consumed, so
// each wave keeps >=6KB outstanding during the ~250-cycle compute phase
// (counted-vmcnt pattern). The compiler's register-minimizing schedule
// (32 VGPRs) had serialized loads; the named prefetch variables force the
// live ranges (expect ~64-96 VGPRs).
__global__ __launch_bounds__(THREADS, 4) void xy_loss_main(
    const float* __restrict__ mask,   // [B,1,H,W]
    const float* __restrict__ scale,  // [B,1,H,W]
    const float* __restrict__ pred,   // [B,2,H,W]
    const float* __restrict__ truth,  // [B,2,H,W]
    float* __restrict__ ws)           // [0..NBLK): S1 parts, [NBLK..2*NBLK): S2 parts
{
    const int g0 = blockIdx.x * THREADS + threadIdx.x;
    const int i0 = g0 << 2;                  // flat pixel index (b*HW + hw)
    const int b0 = i0 + (i0 & ~(HW - 1));    // b*2*HW + hw

    const float* pm = mask  + i0;
    const float* ps = scale + i0;
    const float* pp = pred  + b0;
    const float* pt = truth + b0;

    // prologue: issue iteration 0's loads
    float4 ax0 = *(const float4*)(pp);
    float4 ax1 = *(const float4*)(pp + HW);
    float4 at0 = *(const float4*)(pt);
    float4 at1 = *(const float4*)(pt + HW);
    float4 amk = *(const float4*)(pm);
    float4 asc = *(const float4*)(ps);

    float s1 = 0.0f, s2 = 0.0f;

    #pragma unroll 2
    for (int k = 1; k < ITERS; ++k) {
        pm += 2 * HW; ps += 2 * HW;          // uniform strides -> scalar adds
        pp += 4 * HW; pt += 4 * HW;

        // issue next iteration's loads BEFORE consuming current values
        float4 bx0 = *(const float4*)(pp);
        float4 bx1 = *(const float4*)(pp + HW);
        float4 bt0 = *(const float4*)(pt);
        float4 bt1 = *(const float4*)(pt + HW);
        float4 bmk = *(const float4*)(pm);
        float4 bsc = *(const float4*)(ps);

        // consume current (waits only for batch A: vmcnt(6), B stays in flight)
        s1 += elem_loss(ax0.x, ax1.x, at0.x, at1.x)
            + elem_loss(ax0.y, ax1.y, at0.y, at1.y)
            + elem_loss(ax0.z, ax1.z, at0.z, at1.z)
            + elem_loss(ax0.w, ax1.w, at0.w, at1.w);
        s2 += amk.x * asc.x + amk.y * asc.y + amk.z * asc.z + amk.w * asc.w;

        ax0 = bx0; ax1 = bx1; at0 = bt0; at1 = bt1; amk = bmk; asc = bsc;
    }

    // epilogue: consume last batch
    s1 += elem_loss(ax0.x, ax1.x, at0.x, at1.x)
        + elem_loss(ax0.y, ax1.y, at0.y, at1.y)
        + elem_loss(ax0.z, ax1.z, at0.z, at1.z)
        + elem_loss(ax0.w, ax1.w, at0.w, at1.w);
    s2 += amk.x * asc.x + amk.y * asc.y + amk.z * asc.z + amk.w * asc.w;

    // wave64 shuffle reduction
    #pragma unroll
    for (int off = 32; off > 0; off >>= 1) {
        s1 += __shfl_down(s1, off, 64);
        s2 += __shfl_down(s2, off, 64);
    }

    __shared__ float ls1[4], ls2[4];
    const int lane = threadIdx.x & 63;
    const int wv   = threadIdx.x >> 6;
    if (lane == 0) { ls1[wv] = s1; ls2[wv] = s2; }
    __syncthreads();

    if (threadIdx.x == 0) {
        ws[blockIdx.x]        = ls1[0] + ls1[1] + ls1[2] + ls1[3];
        ws[NBLK + blockIdx.x] = ls2[0] + ls2[1] + ls2[2] + ls2[3];
    }
}

__global__ __launch_bounds__(1024) void xy_finalize(
    const float* __restrict__ ws, float* __restrict__ out)
{
    const int tid = threadIdx.x;
    // NBLK = 2048 partials per array, 1024 threads -> 2 each
    float a = ws[tid]        + ws[tid + 1024];
    float b = ws[NBLK + tid] + ws[NBLK + tid + 1024];

    #pragma unroll
    for (int off = 32; off > 0; off >>= 1) {
        a += __shfl_down(a, off, 64);
        b += __shfl_down(b, off, 64);
    }
    __shared__ float la[16], lb[16];
    const int lane = tid & 63;
    const int wv   = tid >> 6;
    if (lane == 0) { la[wv] = a; lb[wv] = b; }
    __syncthreads();
    if (tid == 0) {
        float s1 = 0.0f, s2 = 0.0f;
        #pragma unroll
        for (int w = 0; w < 16; ++w) { s1 += la[w]; s2 += lb[w]; }
        out[0] = s1 * s2 * (1.0f / (float)NPIX);
    }
}

extern "C" void kernel_launch(void* const* d_in, const int* in_sizes, int n_in,
                              void* d_out, int out_size, void* d_ws, size_t ws_size,
                              hipStream_t stream) {
    const float* mask  = (const float*)d_in[0];  // object_mask    [16,1,1024,1024]
    const float* scale = (const float*)d_in[1];  // box_loss_scale [16,1,1024,1024]
    const float* pred  = (const float*)d_in[2];  // predict_xy     [16,2,1024,1024]
    const float* truth = (const float*)d_in[3];  // true_xy        [16,2,1024,1024]
    float* out = (float*)d_out;
    float* ws  = (float*)d_ws;                   // 2*NBLK floats = 16 KB of partials

    xy_loss_main<<<NBLK, THREADS, 0, stream>>>(mask, scale, pred, truth, ws);
    xy_finalize<<<1, 1024, 0, stream>>>(ws, out);
}

// Round 6
// 324.803 us; speedup vs baseline: 1.0967x; 1.0967x over previous
//
#include <hip/hip_runtime.h>
#include <math.h>

// Problem constants (B=16, C=2, H=1024, W=1024)
#define HW   (1024 * 1024)          // H*W = 1M (power of two)
#define NPIX (16 * HW)              // B*H*W = 16,777,216
#define NGRP (NPIX / 4)             // float4 groups over pixel space = 4,194,304

constexpr int THREADS   = 256;
constexpr int NBLK      = 2048;                    // 8 blocks/CU, grid-stride
constexpr int TOTALTHR  = NBLK * THREADS;          // 524,288 threads
constexpr int ITERS     = NGRP / TOTALTHR;         // 8 float4-groups per thread
static_assert(ITERS * TOTALTHR == NGRP, "exact tiling");
static_assert((ITERS & 1) == 0, "ping-pong needs even ITERS");
// Per-iteration pointer strides are uniform compile-time constants because
// 4*TOTALTHR (2^21) is a multiple of HW (2^20).
constexpr int MS_STR = 2 * HW;   // mask/scale stride per iteration (elements)
constexpr int PT_STR = 4 * HW;   // pred/truth stride per iteration (elements)

typedef float v4f __attribute__((ext_vector_type(4)));

// Non-temporal: no reuse exists within a dispatch, and R4 counters show the
// L3 supplies ~50% of reads with no speedup vs HBM — bypass allocation so
// all 403 MB stream straight from HBM (FETCH_SIZE should rise to ~400 MB).
__device__ __forceinline__ v4f ntload(const float* p) {
    return __builtin_nontemporal_load((const v4f*)p);
}

__device__ __forceinline__ float fast_sigmoid(float x) {
    return __builtin_amdgcn_rcpf(1.0f + __expf(-x));
}

__device__ __forceinline__ float elem_loss(float x0, float x1, float t0, float t1) {
    float p0 = fast_sigmoid(x0);
    float p1 = fast_sigmoid(x1);
    // p0,p1 in (0,1): e^p in (1,e), no stabilization needed
    float lse = __logf(__expf(p0) + __expf(p1));
    return (t0 + t1) * lse - (t0 * p0 + t1 * p1);
}

// R4 post-mortem: VGPR=28 proved the compiler collapsed the rotating
// software pipeline to a load-window of ~1-2 per wave (cannot hold even two
// float4s in 28 regs). This version forces the window with a TRUE ping-pong:
// two named register sets, no rotation copies, full unroll so all indices
// and guards are compile-time constants. Dataflow makes collapse illegal:
// batch B is loaded before batch A is consumed and vice versa.
__global__ __launch_bounds__(THREADS, 4) void xy_loss_main(
    const float* __restrict__ mask,   // [B,1,H,W]
    const float* __restrict__ scale,  // [B,1,H,W]
    const float* __restrict__ pred,   // [B,2,H,W]
    const float* __restrict__ truth,  // [B,2,H,W]
    float* __restrict__ ws)           // [0..NBLK): S1 parts, [NBLK..2*NBLK): S2 parts
{
    const int g0 = blockIdx.x * THREADS + threadIdx.x;
    const int i0 = g0 << 2;                  // flat pixel index (b*HW + hw)
    const int b0 = i0 + (i0 & ~(HW - 1));    // b*2*HW + hw

    const float* pm = mask  + i0;
    const float* ps = scale + i0;
    const float* pp = pred  + b0;
    const float* pt = truth + b0;

    v4f ax0, ax1, at0, at1, amk, asc;   // batch A registers
    v4f bx0, bx1, bt0, bt1, bmk, bsc;   // batch B registers

#define LOAD_A(K) do { \
        ax0 = ntload(pp + (K) * PT_STR); \
        ax1 = ntload(pp + (K) * PT_STR + HW); \
        at0 = ntload(pt + (K) * PT_STR); \
        at1 = ntload(pt + (K) * PT_STR + HW); \
        amk = ntload(pm + (K) * MS_STR); \
        asc = ntload(ps + (K) * MS_STR); \
    } while (0)

#define LOAD_B(K) do { \
        bx0 = ntload(pp + (K) * PT_STR); \
        bx1 = ntload(pp + (K) * PT_STR + HW); \
        bt0 = ntload(pt + (K) * PT_STR); \
        bt1 = ntload(pt + (K) * PT_STR + HW); \
        bmk = ntload(pm + (K) * MS_STR); \
        bsc = ntload(ps + (K) * MS_STR); \
    } while (0)

#define CONSUME_A() do { \
        s1 += elem_loss(ax0.x, ax1.x, at0.x, at1.x) \
            + elem_loss(ax0.y, ax1.y, at0.y, at1.y) \
            + elem_loss(ax0.z, ax1.z, at0.z, at1.z) \
            + elem_loss(ax0.w, ax1.w, at0.w, at1.w); \
        s2 += amk.x * asc.x + amk.y * asc.y + amk.z * asc.z + amk.w * asc.w; \
    } while (0)

#define CONSUME_B() do { \
        s1 += elem_loss(bx0.x, bx1.x, bt0.x, bt1.x) \
            + elem_loss(bx0.y, bx1.y, bt0.y, bt1.y) \
            + elem_loss(bx0.z, bx1.z, bt0.z, bt1.z) \
            + elem_loss(bx0.w, bx1.w, bt0.w, bt1.w); \
        s2 += bmk.x * bsc.x + bmk.y * bsc.y + bmk.z * bsc.z + bmk.w * bsc.w; \
    } while (0)

    float s1 = 0.0f, s2 = 0.0f;

    LOAD_A(0);
    #pragma unroll
    for (int k = 0; k < ITERS; k += 2) {
        LOAD_B(k + 1);                       // issue next batch before consuming A
        CONSUME_A();
        if (k + 2 < ITERS) LOAD_A(k + 2);    // static guard after full unroll
        CONSUME_B();
    }

#undef LOAD_A
#undef LOAD_B
#undef CONSUME_A
#undef CONSUME_B

    // wave64 shuffle reduction
    #pragma unroll
    for (int off = 32; off > 0; off >>= 1) {
        s1 += __shfl_down(s1, off, 64);
        s2 += __shfl_down(s2, off, 64);
    }

    __shared__ float ls1[4], ls2[4];
    const int lane = threadIdx.x & 63;
    const int wv   = threadIdx.x >> 6;
    if (lane == 0) { ls1[wv] = s1; ls2[wv] = s2; }
    __syncthreads();

    if (threadIdx.x == 0) {
        ws[blockIdx.x]        = ls1[0] + ls1[1] + ls1[2] + ls1[3];
        ws[NBLK + blockIdx.x] = ls2[0] + ls2[1] + ls2[2] + ls2[3];
    }
}

__global__ __launch_bounds__(1024) void xy_finalize(
    const float* __restrict__ ws, float* __restrict__ out)
{
    const int tid = threadIdx.x;
    // NBLK = 2048 partials per array, 1024 threads -> 2 each
    float a = ws[tid]        + ws[tid + 1024];
    float b = ws[NBLK + tid] + ws[NBLK + tid + 1024];

    #pragma unroll
    for (int off = 32; off > 0; off >>= 1) {
        a += __shfl_down(a, off, 64);
        b += __shfl_down(b, off, 64);
    }
    __shared__ float la[16], lb[16];
    const int lane = tid & 63;
    const int wv   = tid >> 6;
    if (lane == 0) { la[wv] = a; lb[wv] = b; }
    __syncthreads();
    if (tid == 0) {
        float s1 = 0.0f, s2 = 0.0f;
        #pragma unroll
        for (int w = 0; w < 16; ++w) { s1 += la[w]; s2 += lb[w]; }
        out[0] = s1 * s2 * (1.0f / (float)NPIX);
    }
}

extern "C" void kernel_launch(void* const* d_in, const int* in_sizes, int n_in,
                              void* d_out, int out_size, void* d_ws, size_t ws_size,
                              hipStream_t stream) {
    const float* mask  = (const float*)d_in[0];  // object_mask    [16,1,1024,1024]
    const float* scale = (const float*)d_in[1];  // box_loss_scale [16,1,1024,1024]
    const float* pred  = (const float*)d_in[2];  // predict_xy     [16,2,1024,1024]
    const float* truth = (const float*)d_in[3];  // true_xy        [16,2,1024,1024]
    float* out = (float*)d_out;
    float* ws  = (float*)d_ws;                   // 2*NBLK floats = 16 KB of partials

    xy_loss_main<<<NBLK, THREADS, 0, stream>>>(mask, scale, pred, truth, ws);
    xy_finalize<<<1, 1024, 0, stream>>>(ws, out);
}